// Round 8
// baseline (135.978 us; speedup 1.0000x reference)
//
#include <hip/hip_runtime.h>
#include <hip/hip_fp16.h>

#define CH      64    // IN_CH == OUT_CH == 64
#define BSHIFT  7     // 128 nodes per bucket
#define BNODES  128
#define MAXBUK  400   // NBUK = ceil(50000/128) = 391
#define CAP     4608  // bucket capacity: mean 4096, sigma~64 -> 8-sigma margin
#define HCAP    2688  // half-bucket capacity: mean 2048, sigma~45 -> 10-sigma
#define BTILE   4096  // R2 falsified 2048 (+7.3us): per-tile fixed costs dominate

union H2U { __half2 h; unsigned u; };

typedef _Float16 f16x8 __attribute__((ext_vector_type(8)));
typedef float    f32x4 __attribute__((ext_vector_type(4)));
union U4H8 { uint4 u; f16x8 h; };

// ---------------------------------------------------------------------------
// Launch 1: init — zero per-bucket cursors; build Wt fp16 [128][64]:
//   Wt[c][k] = W1[k][c]      (c <  64, feeds Y1 = x@W1)
//   Wt[c][k] = W2[k][c-64]   (c >= 64, feeds Y2 = x@W2)
// (R4 lesson: hipMemsetAsync inside kernel_launch is a graph-capture risk.)
// ---------------------------------------------------------------------------
__global__ __launch_bounds__(256) void init_kernel(
    int* __restrict__ qcur, int NBUK,
    const float* __restrict__ W, __half* __restrict__ Wt)
{
    for (int i = threadIdx.x; i < NBUK; i += 256) qcur[i] = 0;
    for (int i = threadIdx.x; i < 128 * 64; i += 256) {
        int c = i >> 6, k = i & 63;
        float v = (c < 64) ? W[k * 64 + c] : W[(64 + k) * 64 + (c - 64)];
        Wt[i] = __float2half(v);
    }
}

// ---------------------------------------------------------------------------
// Launch 2: binprep — heterogeneous blocks (UNCHANGED from R7-proven body).
//   blocks [0, EB):      bin tiles (single-atomic rank) -> qm (u32) / qa (fp16)
//   blocks [EB, EB+YB):  Y = x @ [W1|W2] via mfma_f32_16x16x32_f16,
//                        swapped operands (A=W-frag) -> packed 8B y-stores.
// ---------------------------------------------------------------------------
__global__ __launch_bounds__(512) void binprep_kernel(
    const int* __restrict__ ei, const float* __restrict__ attr,
    int* __restrict__ qcur, unsigned* __restrict__ qm, __half* __restrict__ qa,
    int E, int NBUK,
    const float* __restrict__ x, const __half* __restrict__ Wt,
    __half* __restrict__ y1h, __half* __restrict__ y2h, int N, int EB)
{
    __shared__ int   lcnt[MAXBUK];
    __shared__ int   loff[MAXBUK];
    __shared__ int   gloc[MAXBUK];    // local (0-based) reserved base per bucket
    __shared__ int   wsum[8];
    __shared__ uint2 stg[BTILE];      // 32 KB

    int t = threadIdx.x, wv = t >> 6, ln = t & 63;

    if ((int)blockIdx.x >= EB) {      // ---- Y-GEMM blocks (swapped operands) ----
        int yb   = blockIdx.x - EB;
        int jrow = ln & 15;           // x-row within the wave's 16
        int kg   = ln >> 4;           // k-group (8 contiguous k)
        int n0   = yb * 128 + wv * 16;
        if (n0 >= N) return;
        int xrow  = n0 + jrow;
        int xrowc = xrow < N ? xrow : N - 1;

        f16x8 xfr[2];
        #pragma unroll
        for (int s = 0; s < 2; ++s) {
            const float* xp = x + (size_t)xrowc * 64 + s * 32 + kg * 8;
            float4 v0 = *(const float4*)xp;
            float4 v1 = *(const float4*)(xp + 4);
            f16x8 a;
            a[0]=(_Float16)v0.x; a[1]=(_Float16)v0.y;
            a[2]=(_Float16)v0.z; a[3]=(_Float16)v0.w;
            a[4]=(_Float16)v1.x; a[5]=(_Float16)v1.y;
            a[6]=(_Float16)v1.z; a[7]=(_Float16)v1.w;
            xfr[s] = a;
        }
        #pragma unroll
        for (int ot = 0; ot < 8; ++ot) {
            f32x4 acc = {0.f, 0.f, 0.f, 0.f};
            #pragma unroll
            for (int s = 0; s < 2; ++s) {
                U4H8 wu;   // A-frag: w-cols tile ot, row=jrow, k=kg*8+s*32
                wu.u = *(const uint4*)(Wt + ((ot * 16 + jrow) * 64 + s * 32 + kg * 8));
                acc = __builtin_amdgcn_mfma_f32_16x16x32_f16(wu.h, xfr[s], acc, 0, 0, 0);
            }
            // D: col(lane&15)=x-row=jrow; row=(lane>>4)*4+reg = w-col-local
            if (xrow < N) {
                __half* yp = (ot < 4) ? y1h : y2h;
                int cl = (ot & 3) * 16 + kg * 4;   // local col base (mult of 4)
                H2U p0, p1;
                p0.h = __floats2half2_rn(acc[0], acc[1]);
                p1.h = __floats2half2_rn(acc[2], acc[3]);
                *(uint2*)(yp + (size_t)xrow * 64 + cl) = make_uint2(p0.u, p1.u);
            }
        }
        return;
    }

    // ---- bin tile (R5-proven body) ----
    int tbase = blockIdx.x * BTILE;
    int m = E - tbase; if (m > BTILE) m = BTILE;

    for (int i = t; i < NBUK; i += 512) lcnt[i] = 0;
    __syncthreads();

    int ebase = tbase + t * 8;
    int ne = m - t * 8; ne = ne < 0 ? 0 : (ne > 8 ? 8 : ne);

    int rows[8], cols[8]; float av[8];
    if (ne == 8) {
        int4 r0 = *(const int4*)(ei + ebase);
        int4 r1 = *(const int4*)(ei + ebase + 4);
        int4 c0 = *(const int4*)(ei + E + ebase);
        int4 c1 = *(const int4*)(ei + E + ebase + 4);
        float4 a0 = *(const float4*)(attr + ebase);
        float4 a1 = *(const float4*)(attr + ebase + 4);
        rows[0]=r0.x; rows[1]=r0.y; rows[2]=r0.z; rows[3]=r0.w;
        rows[4]=r1.x; rows[5]=r1.y; rows[6]=r1.z; rows[7]=r1.w;
        cols[0]=c0.x; cols[1]=c0.y; cols[2]=c0.z; cols[3]=c0.w;
        cols[4]=c1.x; cols[5]=c1.y; cols[6]=c1.z; cols[7]=c1.w;
        av[0]=a0.x; av[1]=a0.y; av[2]=a0.z; av[3]=a0.w;
        av[4]=a1.x; av[5]=a1.y; av[6]=a1.z; av[7]=a1.w;
    } else {
        #pragma unroll
        for (int j = 0; j < 8; ++j) {
            if (j < ne) { rows[j]=ei[ebase+j]; cols[j]=ei[E+ebase+j]; av[j]=attr[ebase+j]; }
            else        { rows[j]=0; cols[j]=0; av[j]=0.f; }
        }
    }

    // single pass: histogram atomic's return IS the within-tile rank
    int rk[8];
    #pragma unroll
    for (int j = 0; j < 8; ++j)
        if (j < ne) rk[j] = atomicAdd(&lcnt[rows[j] >> BSHIFT], 1);
    __syncthreads();

    // shfl-based exclusive scan of lcnt
    int v = (t < NBUK) ? lcnt[t] : 0;
    int inc = v;
    #pragma unroll
    for (int d = 1; d < 64; d <<= 1) {
        int u = __shfl_up(inc, d);
        if (ln >= d) inc += u;
    }
    if (ln == 63) wsum[wv] = inc;
    __syncthreads();
    if (wv == 0) {
        int s = (ln < 8) ? wsum[ln] : 0;
        int si = s;
        #pragma unroll
        for (int d = 1; d < 8; d <<= 1) {
            int u = __shfl_up(si, d);
            if (ln >= d) si += u;
        }
        if (ln < 8) wsum[ln] = si - s;
    }
    __syncthreads();
    if (t < NBUK) {
        loff[t] = inc - v + wsum[wv];
        if (v > 0) gloc[t] = atomicAdd(&qcur[t], v);
    }
    __syncthreads();

    #pragma unroll
    for (int j = 0; j < 8; ++j) {
        if (j < ne) {
            int bk = rows[j] >> BSHIFT;
            unsigned meta = ((unsigned)bk << 23) |
                            ((unsigned)(rows[j] & (BNODES - 1)) << 16) |
                            (unsigned)cols[j];
            stg[loff[bk] + rk[j]] = make_uint2(meta, __float_as_uint(av[j]));
        }
    }
    __syncthreads();

    for (int i = t; i < m; i += 512) {
        uint2 e = stg[i];
        int bk = (int)(e.x >> 23);
        int lp = gloc[bk] + (i - loff[bk]);
        if (lp < CAP) {                        // overflow guard (8-sigma)
            size_t o = (size_t)bk * CAP + lp;
            qm[o] = e.x;                       // coalesced-run writes
            qa[o] = __float2half(__uint_as_float(e.y));
        }
    }
}

// ---------------------------------------------------------------------------
// Launch 3: fused sort + gather + epilogue.
// R8 change: HALF-bucket siblings — 2 blocks per bucket, 64 nodes each (was
// 4 x 32).  Chip-total stage redundancy halves (each bucket scanned 2x not
// 4x: 43 -> 21.5 MB q reads, predicate work halved).  Each 16-lane group now
// owns 2 nodes serially.  Rank pack {r:6 | rank:10} (max real 63*1024+~100
// < 0xffff sentinel).  Stage mechanics (R6 register sort) and inner loop
// (R7 node-per-16-lane) otherwise unchanged.
// ---------------------------------------------------------------------------
__global__ __launch_bounds__(512, 8) void gather_out_kernel(
    const __half* __restrict__ y1h,
    const __half* __restrict__ y2h,
    const unsigned* __restrict__ qm,
    const __half* __restrict__ qa,
    const int* __restrict__ qcur,
    const float* __restrict__ bias,
    float* __restrict__ out,
    int N, int NBUK, int chunk)
{
    __shared__ unsigned srt[HCAP];      // 10.5 KB  packed {col<<16|attr_h}
    __shared__ int ncnt[64];
    __shared__ int nst[64];

    int t  = threadIdx.x;
    int ln = t & 63;

    // XCD-aware bijective swizzle (phys%8 == XCD heuristic; perf-only)
    int lb = ((int)blockIdx.x & 7) * chunk + ((int)blockIdx.x >> 3);
    int b  = lb >> 1;                   // bucket
    int hf = lb & 1;                    // 64-node half within bucket
    if (b >= NBUK) return;              // padded blocks; uniform, pre-barrier

    if (t < 64) ncnt[t] = 0;
    __syncthreads();

    int cnt = qcur[b]; if (cnt > CAP) cnt = CAP;   // uniform -> scalar load
    size_t base = (size_t)b * CAP;

    // ---- phase 1: scan bucket (2 entries/thread/iter), rank in registers ----
    unsigned sval[5][2];
    unsigned srr[5];                    // two 16-bit {r(6)<<10 | rank(10)}
    int nit = (cnt + 1023) >> 10;
    for (int it = 0; it < 5; ++it) {
        unsigned m0 = 0xffffu, m1 = 0xffffu;   // sentinel: invalid
        if (it < nit) {
            int i0 = it * 1024 + t * 2;
            if (i0 + 2 <= cnt) {               // both entries in range (common)
                uint2 mv = *(const uint2*)(qm + base + i0);
                H2U  ah;  ah.u = *(const unsigned*)(qa + base + i0);
                if ((int)((mv.x >> 22) & 1u) == hf) {
                    int r = (int)((mv.x >> 16) & 63u);
                    int rk = atomicAdd(&ncnt[r], 1);
                    sval[it][0] = ((mv.x & 0xffffu) << 16) | (ah.u & 0xffffu);
                    m0 = ((unsigned)r << 10) | (unsigned)(rk & 0x3ff);
                }
                if ((int)((mv.y >> 22) & 1u) == hf) {
                    int r = (int)((mv.y >> 16) & 63u);
                    int rk = atomicAdd(&ncnt[r], 1);
                    sval[it][1] = ((mv.y & 0xffffu) << 16) | (ah.u >> 16);
                    m1 = ((unsigned)r << 10) | (unsigned)(rk & 0x3ff);
                }
            } else {                            // ragged tail: scalar path
                #pragma unroll
                for (int s = 0; s < 2; ++s) {
                    int i = i0 + s;
                    if (i < cnt) {
                        unsigned mv = qm[base + i];
                        if ((int)((mv >> 22) & 1u) == hf) {
                            int r = (int)((mv >> 16) & 63u);
                            int rk = atomicAdd(&ncnt[r], 1);
                            unsigned ah = (unsigned)__half_as_ushort(qa[base + i]);
                            sval[it][s] = ((mv & 0xffffu) << 16) | ah;
                            unsigned mm = ((unsigned)r << 10) | (unsigned)(rk & 0x3ff);
                            if (s == 0) m0 = mm; else m1 = mm;
                        }
                    }
                }
            }
        }
        srr[it] = m0 | (m1 << 16);
    }
    __syncthreads();

    // ---- scan 64 counters (wave 0, full 64-lane scan) ----
    if (t < 64) {
        int v = ncnt[t];
        int inc = v;
        #pragma unroll
        for (int d = 1; d < 64; d <<= 1) {
            int u = __shfl_up(inc, d);
            if (ln >= d) inc += u;
        }
        nst[t] = inc - v;
    }
    __syncthreads();

    // ---- phase 2: place from registers (rank + nst = final position) ----
    #pragma unroll
    for (int it = 0; it < 5; ++it) {
        unsigned m0 = srr[it] & 0xffffu, m1 = srr[it] >> 16;
        if (m0 != 0xffffu) {
            int p = nst[m0 >> 10] + (int)(m0 & 0x3ff);
            if (p < HCAP) srt[p] = sval[it][0];
        }
        if (m1 != 0xffffu) {
            int p = nst[m1 >> 10] + (int)(m1 & 0x3ff);
            if (p < HCAP) srt[p] = sval[it][1];
        }
    }
    __syncthreads();

    // ---- gather + epilogue: node-per-16-lane, 2 nodes serial per group ----
    int w   = t >> 6;        // wave in block (0..7)
    int grp = ln >> 4;       // group within wave (0..3)
    int l   = ln & 15;       // channel-quad
    int gid = w * 4 + grp;   // group id 0..31

    #pragma unroll
    for (int k = 0; k < 2; ++k) {
        int nl = gid * 2 + k;                 // local node 0..63
        int n  = b * BNODES + hf * 64 + nl;
        bool alive = (n < N);

        int start = nst[nl];
        int deg   = ncnt[nl];
        int end   = alive ? start + deg : start;   // zero-trip if dead

        float a0 = 0.f, a1 = 0.f, a2 = 0.f, a3 = 0.f, sa = 0.f;
        for (int cb = start; cb < end; cb += 8) {      // 8 edges per batch
            unsigned v[8];
            #pragma unroll
            for (int j = 0; j < 8; ++j) {              // srt reads (broadcast)
                int  idx = cb + j;
                bool act = idx < end;
                unsigned vv = srt[act ? idx : end - 1];
                v[j] = act ? vv : (vv & 0xffff0000u);  // zero attr if padding
            }
            uint2 u[8];
            #pragma unroll
            for (int j = 0; j < 8; ++j)                // 8 independent row loads
                u[j] = *(const uint2*)(y2h + (((size_t)(v[j] >> 16)) << 6) + (l << 2));
            #pragma unroll
            for (int j = 0; j < 8; ++j) {              // consume
                float a = __half2float(__ushort_as_half((unsigned short)(v[j] & 0xffffu)));
                H2U u0, u1; u0.u = u[j].x; u1.u = u[j].y;
                float2 f0 = __half22float2(u0.h);
                float2 f1 = __half22float2(u1.h);
                a0 += a * f0.x; a1 += a * f0.y; a2 += a * f1.x; a3 += a * f1.y;
                sa += a;
            }
        }

        if (alive) {
            uint2 y1u = *(const uint2*)(y1h + (size_t)n * CH + l * 4);
            H2U h0, h1; h0.u = y1u.x; h1.u = y1u.y;
            float2 f0 = __half22float2(h0.h);
            float2 f1 = __half22float2(h1.h);
            float4 bv = *(const float4*)(bias + l * 4);
            float c = (float)deg;
            if (c < 1.0f) c = 1.0f;
            float4 o;
            o.x = (sa * f0.x + a0) / c + bv.x;
            o.y = (sa * f0.y + a1) / c + bv.y;
            o.z = (sa * f1.x + a2) / c + bv.z;
            o.w = (sa * f1.y + a3) / c + bv.w;
            *(float4*)(out + (size_t)n * CH + l * 4) = o;
        }
    }
}

extern "C" void kernel_launch(void* const* d_in, const int* in_sizes, int n_in,
                              void* d_out, int out_size, void* d_ws, size_t ws_size,
                              hipStream_t stream) {
    const float* x    = (const float*)d_in[0];   // [N, 64] f32
    const int*   ei   = (const int*)d_in[1];     // [2, E] int
    const float* attr = (const float*)d_in[2];   // [E] f32
    const float* W    = (const float*)d_in[3];   // [128, 64] f32
    const float* bias = (const float*)d_in[4];   // [64] f32
    float*       out  = (float*)d_out;           // [N, 64] f32

    int N = in_sizes[0] / CH;     // 50000 (col fits 16 bits; NBUK <= MAXBUK)
    int E = in_sizes[2];          // 1,600,000

    int NBUK = (N + BNODES - 1) >> BSHIFT;   // 391

    // Workspace (~23.6 MB <= proven 26.2 MB), alignment-ordered:
    //   Wt[128*64 half] (16B-aligned for uint4 frag reads)
    //   y1h[N*64 half] | y2h[N*64 half] (8B-aligned: gather uint2 reads)
    //   qm[NBUK*CAP u32] | qa[NBUK*CAP half] | qcur[NBUK]
    __half*   Wt   = (__half*)d_ws;
    __half*   y1h  = Wt + 128 * 64;
    __half*   y2h  = y1h + (size_t)N * CH;
    unsigned* qm   = (unsigned*)(y2h + (size_t)N * CH);
    __half*   qa   = (__half*)(qm + (size_t)NBUK * CAP);
    int*      qcur = (int*)(qa + (size_t)NBUK * CAP);

    init_kernel<<<1, 256, 0, stream>>>(qcur, NBUK, W, Wt);

    int EB = (E + BTILE - 1) / BTILE;    // 391 bin tiles
    int YB = (N + 127) / 128;            // 391 Y-GEMM blocks (8 waves x 16 rows)
    binprep_kernel<<<EB + YB, 512, 0, stream>>>(
        ei, attr, qcur, qm, qa, E, NBUK, x, Wt, y1h, y2h, N, EB);

    // fused sort+gather: 2 blocks per bucket, grid padded to mult of 32 so
    // the XCD swizzle is bijective and bucket-pairs never straddle chunks
    // (chunk = 100, even).
    int NQ = NBUK * 2;                   // 782
    int G  = (NQ + 31) & ~31;            // 800 = 8 * 100
    int chunk = G >> 3;                  // 100 (even)
    gather_out_kernel<<<G, 512, 0, stream>>>(
        y1h, y2h, qm, qa, qcur, bias, out, N, NBUK, chunk);
}